// Round 21
// baseline (219.159 us; speedup 1.0000x reference)
//
#include <hip/hip_runtime.h>
#include <hip/hip_bf16.h>
#include <stdint.h>

#define DEVI __device__ __forceinline__

typedef float  f32x4 __attribute__((ext_vector_type(4)));
typedef short  s16x8 __attribute__((ext_vector_type(8)));

DEVI unsigned short bfbits(float f) {
  __hip_bfloat16 h = __float2bfloat16(f);
  return __builtin_bit_cast(unsigned short, h);
}
DEVI float b2f(unsigned short u) {
  unsigned int x = ((unsigned int)u) << 16;
  return __builtin_bit_cast(float, x);
}

DEVI void mfma_bf16(f32x4& d, s16x8 a, s16x8 b) {
  asm("v_mfma_f32_16x16x32_bf16 %0, %1, %2, %0" : "+v"(d) : "v"(a), "v"(b));
}

DEVI void gload_lds16(const void* g, void* l) {
  __builtin_amdgcn_global_load_lds(
      (const __attribute__((address_space(1))) void*)g,
      (__attribute__((address_space(3))) void*)l, 16, 0, 0);
}

// ---------------- fp32 -> bf16 convert, all three tensors in one launch ----
__global__ void cvtk3(const float4* __restrict__ sx, const float4* __restrict__ sq,
                      const float4* __restrict__ sw, ushort4* __restrict__ dx,
                      ushort4* __restrict__ dq, ushort4* __restrict__ dw) {
  const int N1 = 2097152;            // x: 8192*1024/4
  const int N2 = 786432;             // Wqkv: 3072*1024/4
  const int N3 = 262144;             // Wout: 1024*1024/4
  int i = blockIdx.x * blockDim.x + threadIdx.x;
  int st = gridDim.x * blockDim.x;
  for (; i < N1 + N2 + N3; i += st) {
    const float4* s; ushort4* d; int j;
    if (i < N1)            { s = sx; d = dx; j = i; }
    else if (i < N1 + N2)  { s = sq; d = dq; j = i - N1; }
    else                   { s = sw; d = dw; j = i - N1 - N2; }
    float4 v = s[j];
    ushort4 o;
    o.x = bfbits(v.x); o.y = bfbits(v.y); o.z = bfbits(v.z); o.w = bfbits(v.w);
    d[j] = o;
  }
}

// ---------------- GEMM: C[M,N] = A[M,K] * BT[N,K]^T  (bf16 in, fp32 acc) ----
template<int EPI>
__global__ __launch_bounds__(256, 3) void gemm_k(
    const unsigned short* __restrict__ A,
    const unsigned short* __restrict__ BT,
    unsigned short* __restrict__ q_ws,
    unsigned short* __restrict__ k_ws,
    unsigned short* __restrict__ vt_ws,
    float* __restrict__ Cout)
{
  constexpr int K = 1024;
  __shared__ __align__(16) unsigned short Als[128 * 64];
  __shared__ __align__(16) unsigned short Bls[128 * 64];

  const int tid = threadIdx.x;
  const int w = tid >> 6, l = tid & 63;
  const int g = l >> 4, c = l & 15;
  const int wm = w >> 1, wn = w & 1;
  const int nb = blockIdx.x, mb = blockIdx.y;

  int srow[4], skof[4];
#pragma unroll
  for (int it = 0; it < 4; ++it) {
    int idx = (w * 4 + it) * 64 + l;
    srow[it] = idx >> 3;
    skof[it] = ((idx & 7) ^ (srow[it] & 7)) << 3;
  }

  f32x4 acc[4][4] = {};
  const unsigned short* Ab = A + (size_t)(mb * 128) * K;
  const unsigned short* Bb = BT + (size_t)(nb * 128) * K;

  for (int kt = 0; kt < K / 64; ++kt) {
    __syncthreads();
#pragma unroll
    for (int it = 0; it < 4; ++it) {
      gload_lds16(Ab + (size_t)srow[it] * K + kt * 64 + skof[it], &Als[(w * 4 + it) * 512]);
      gload_lds16(Bb + (size_t)srow[it] * K + kt * 64 + skof[it], &Bls[(w * 4 + it) * 512]);
    }
    __syncthreads();
#pragma unroll
    for (int kk = 0; kk < 2; ++kk) {
      s16x8 af[4], bfv[4];
#pragma unroll
      for (int mi = 0; mi < 4; ++mi) {
        int row = wm * 64 + mi * 16 + c;
        int slot = (kk * 4 + g) ^ (row & 7);
        af[mi] = *(const s16x8*)&Als[row * 64 + slot * 8];
      }
#pragma unroll
      for (int ni = 0; ni < 4; ++ni) {
        int row = wn * 64 + ni * 16 + c;
        int slot = (kk * 4 + g) ^ (row & 7);
        bfv[ni] = *(const s16x8*)&Bls[row * 64 + slot * 8];
      }
#pragma unroll
      for (int mi = 0; mi < 4; ++mi)
#pragma unroll
        for (int ni = 0; ni < 4; ++ni)
          mfma_bf16(acc[mi][ni], af[mi], bfv[ni]);
    }
  }

  if constexpr (EPI == 0) {
    const int csec = (nb * 128) >> 10;
#pragma unroll
    for (int mi = 0; mi < 4; ++mi) {
#pragma unroll
      for (int ni = 0; ni < 4; ++ni) {
        int ncol = nb * 128 + wn * 64 + ni * 16 + c;
        int f = ncol & 1023;
        int hh = f >> 6, dd = f & 63;
#pragma unroll
        for (int r = 0; r < 4; ++r) {
          int m = mb * 128 + wm * 64 + mi * 16 + 4 * g + r;
          int bb = m >> 11, ss = m & 2047;
          int bh = bb * 16 + hh;
          float v = acc[mi][ni][r];
          if (csec == 0)      q_ws[((size_t)bh * 2048 + ss) * 64 + dd] = bfbits(v * 0.125f);
          else if (csec == 1) k_ws[((size_t)bh * 2048 + ss) * 64 + dd] = bfbits(v);
          else                vt_ws[((size_t)bh * 64 + dd) * 2048 + ss] = bfbits(v);
        }
      }
    }
  } else {
#pragma unroll
    for (int mi = 0; mi < 4; ++mi)
#pragma unroll
      for (int ni = 0; ni < 4; ++ni) {
        int ncol = nb * 128 + wn * 64 + ni * 16 + c;
#pragma unroll
        for (int r = 0; r < 4; ++r) {
          int m = mb * 128 + wm * 64 + mi * 16 + 4 * g + r;
          Cout[(size_t)m * 1024 + ncol] = acc[mi][ni][r];
        }
      }
  }
}

// ---------------- flash attention (R20 loop + R13-proven KV-split-2) -------
// Round 21: inner loop/protocol byte-identical to R20 (proven). SPLIT=1 adds
// the R13-proven grid KV-split (pointer-offset-only; decode on bidq is
// unchanged): 1024 blocks -> 4 blocks/CU -> 4 waves/SIMD, hiding the
// barrier-drain stalls R20 exposed (35% stall at 2 waves/SIMD).
// Swizzle (bijective over 1024): flat=(bid&7)*128+(bid>>3); kvh=flat&1;
// bidq=flat>>1 -> XCD x owns bh in [8x,8x+8), both kv halves.
// m==0 softmax makes halves exactly additive: out=(oA+oB)/(lA+lB) (mergek).
template<int SPLIT>
__global__ __launch_bounds__(256) void attn_k(
    const unsigned short* __restrict__ q_ws,
    const unsigned short* __restrict__ k_ws,
    const unsigned short* __restrict__ vt_ws,
    unsigned short* __restrict__ a_ws,      // SPLIT=0 out
    unsigned short* __restrict__ opA,       // SPLIT=1 outs
    unsigned short* __restrict__ opB,
    float* __restrict__ lA,
    float* __restrict__ lB)
{
  __shared__ __align__(16) unsigned short Klds[32 * 64];   // [kvrow][d], swz slot^=(row&7)
  __shared__ __align__(16) unsigned short Vlds[64 * 32];   // [d][kvcol], swz slot^=((row>>1)&3)
  __shared__ __align__(16) unsigned short P[4][64][40];    // per-wave [q][kpos]
  const int tid = threadIdx.x;
  const int w = tid >> 6, l = tid & 63;
  const int g = l >> 4, c = l & 15;
  const int bid = blockIdx.x;
  int bidq, kvh;
  if constexpr (SPLIT) {
    int flat = (bid & 7) * 128 + (bid >> 3);   // bijective over 1024 = 8*128
    kvh = flat & 1;
    bidq = flat >> 1;                          // [0,512)
  } else {
    bidq = (bid & 7) * 64 + (bid >> 3);        // bijective over 512 = 8*64
    kvh = 0;
  }
  const int wid = bidq * 4 + w;
  const int bh = wid >> 5, qt = wid & 31;
  const int b = bh >> 4, h = bh & 15;
  const int qbase = qt * 64;
  const int KVLEN = SPLIT ? 1024 : 2048;

  const unsigned short* qp = q_ws + (size_t)bh * 2048 * 64;
  const unsigned short* kp = k_ws + (size_t)bh * 2048 * 64 + (size_t)(kvh * 1024) * 64;
  const unsigned short* vp = vt_ws + (size_t)bh * 64 * 2048 + (size_t)(kvh * 1024);

  const int krow  = 8 * w + (l >> 3);
  const int kslot = (l & 7) ^ (l >> 3);
  const int vrow  = 16 * w + (l >> 2);
  const int vslot = (l & 3) ^ ((l >> 3) & 3);

  s16x8 qa[4][2];
#pragma unroll
  for (int mi = 0; mi < 4; ++mi)
#pragma unroll
    for (int kk = 0; kk < 2; ++kk)
      qa[mi][kk] = *(const s16x8*)&qp[(size_t)(qbase + mi * 16 + c) * 64 + kk * 32 + g * 8];

  f32x4 o[4][4] = {};  // o[dt][mi]: O^T[d = dt*16+4g+r][q = mi*16+c]
  float lrun[4];
#pragma unroll
  for (int mi = 0; mi < 4; ++mi) lrun[mi] = 0.f;

  for (int kv = 0; kv < KVLEN; kv += 32) {
    __syncthreads();  // all waves done reading previous tile's Klds/Vlds
    gload_lds16(kp + (size_t)(kv + krow) * 64 + kslot * 8, &Klds[w * 512]);
    gload_lds16(vp + (size_t)vrow * 2048 + kv + vslot * 8, &Vlds[w * 512]);
    __syncthreads();  // staging complete (compiler drains vmcnt before barrier)

    s16x8 kb[2][2];
#pragma unroll
    for (int nt = 0; nt < 2; ++nt)
#pragma unroll
      for (int kk = 0; kk < 2; ++kk) {
        int row = nt * 16 + c;
        kb[nt][kk] = *(const s16x8*)&Klds[row * 64 + (((kk * 4 + g) ^ (row & 7)) * 8)];
      }

    f32x4 st[4][2] = {};
#pragma unroll
    for (int kk = 0; kk < 2; ++kk)
#pragma unroll
      for (int mi = 0; mi < 4; ++mi)
#pragma unroll
        for (int nt = 0; nt < 2; ++nt)
          mfma_bf16(st[mi][nt], kb[nt][kk], qa[mi][kk]);  // S^T = K * Q^T

#pragma unroll
    for (int mi = 0; mi < 4; ++mi) {
      f32x4 s0 = st[mi][0], s1 = st[mi][1];
      ushort4 w0, w1;
      float p00 = __expf(s0[0]), p01 = __expf(s0[1]);
      float p02 = __expf(s0[2]), p03 = __expf(s0[3]);
      float p10 = __expf(s1[0]), p11 = __expf(s1[1]);
      float p12 = __expf(s1[2]), p13 = __expf(s1[3]);
      lrun[mi] += ((p00 + p01) + (p02 + p03)) + ((p10 + p11) + (p12 + p13));
      w0.x = bfbits(p00); w0.y = bfbits(p01); w0.z = bfbits(p02); w0.w = bfbits(p03);
      w1.x = bfbits(p10); w1.y = bfbits(p11); w1.z = bfbits(p12); w1.w = bfbits(p13);
      *(ushort4*)&P[w][mi * 16 + c][4 * g]      = w0;   // ds_write_b64
      *(ushort4*)&P[w][mi * 16 + c][16 + 4 * g] = w1;
    }

    // FENCE: P writes drained, no compiler motion across (rule #18)
    asm volatile("s_waitcnt lgkmcnt(0)" ::: "memory");
    __builtin_amdgcn_sched_barrier(0);

    s16x8 pa[4], vb[4];
#pragma unroll
    for (int mi = 0; mi < 4; ++mi)
      pa[mi] = *(const s16x8*)&P[w][mi * 16 + c][g * 8];

    __builtin_amdgcn_sched_barrier(0);
    asm volatile("" ::: "memory");

#pragma unroll
    for (int dt = 0; dt < 4; ++dt) {
      int rd = dt * 16 + c;
      vb[dt] = *(const s16x8*)&Vlds[rd * 32 + ((g ^ ((rd >> 1) & 3)) * 8)];
    }
#pragma unroll
    for (int dt = 0; dt < 4; ++dt)
#pragma unroll
      for (int mi = 0; mi < 4; ++mi)
        mfma_bf16(o[dt][mi], vb[dt], pa[mi]);  // O^T += V^T * P^T
  }

  if constexpr (SPLIT == 0) {
#pragma unroll
    for (int mi = 0; mi < 4; ++mi) {
      float lv = lrun[mi];
      lv += __shfl_xor(lv, 16);
      lv += __shfl_xor(lv, 32);
      float inv = 1.0f / lv;
      size_t base = ((size_t)(b * 2048 + qbase + mi * 16 + c)) * 1024 + h * 64;
#pragma unroll
      for (int dt = 0; dt < 4; ++dt) {
        ushort4 ov;
        ov.x = bfbits(o[dt][mi][0] * inv);
        ov.y = bfbits(o[dt][mi][1] * inv);
        ov.z = bfbits(o[dt][mi][2] * inv);
        ov.w = bfbits(o[dt][mi][3] * inv);
        *(ushort4*)&a_ws[base + dt * 16 + 4 * g] = ov;  // 8B packed store
      }
    }
  } else {
    unsigned short* op = kvh ? opB : opA;
    float* lp = kvh ? lB : lA;
#pragma unroll
    for (int mi = 0; mi < 4; ++mi) {
      float lv = lrun[mi];
      lv += __shfl_xor(lv, 16);
      lv += __shfl_xor(lv, 32);
      int srow = qbase + mi * 16 + c;
      if (g == 0) lp[bh * 2048 + srow] = lv;   // row-total l (uniform over g)
      size_t base = ((size_t)(b * 2048 + srow)) * 1024 + h * 64;
#pragma unroll
      for (int dt = 0; dt < 4; ++dt) {
        ushort4 ov;
        ov.x = bfbits(o[dt][mi][0]);
        ov.y = bfbits(o[dt][mi][1]);
        ov.z = bfbits(o[dt][mi][2]);
        ov.w = bfbits(o[dt][mi][3]);
        *(ushort4*)&op[base + dt * 16 + 4 * g] = ov;  // unnormalized partial
      }
    }
  }
}

// ---------------- split merge: out = (oA+oB)/(lA+lB), in-place over opA ----
__global__ __launch_bounds__(256) void mergek(
    unsigned short* __restrict__ opA,        // in-out (becomes a_ws)
    const unsigned short* __restrict__ opB,
    const float* __restrict__ lA,
    const float* __restrict__ lB)
{
  int i = blockIdx.x * 256 + threadIdx.x;    // 1,048,576 chunks of 8
  int col = (i & 127) * 8;
  int rowf = i >> 7;                          // b*2048 + s
  int bb = rowf >> 11, ss = rowf & 2047;
  int hh = col >> 6;
  float linv = 1.0f / (lA[(bb * 16 + hh) * 2048 + ss] + lB[(bb * 16 + hh) * 2048 + ss]);
  size_t off = (size_t)rowf * 1024 + col;
  ushort4 a0 = *(ushort4*)&opA[off], a1 = *(ushort4*)&opA[off + 4];
  ushort4 b0 = *(const ushort4*)&opB[off], b1 = *(const ushort4*)&opB[off + 4];
  ushort4 r0, r1;
  r0.x = bfbits((b2f(a0.x) + b2f(b0.x)) * linv);
  r0.y = bfbits((b2f(a0.y) + b2f(b0.y)) * linv);
  r0.z = bfbits((b2f(a0.z) + b2f(b0.z)) * linv);
  r0.w = bfbits((b2f(a0.w) + b2f(b0.w)) * linv);
  r1.x = bfbits((b2f(a1.x) + b2f(b1.x)) * linv);
  r1.y = bfbits((b2f(a1.y) + b2f(b1.y)) * linv);
  r1.z = bfbits((b2f(a1.z) + b2f(b1.z)) * linv);
  r1.w = bfbits((b2f(a1.w) + b2f(b1.w)) * linv);
  *(ushort4*)&opA[off]     = r0;
  *(ushort4*)&opA[off + 4] = r1;
}

// ---------------- launcher ----------------
extern "C" void kernel_launch(void* const* d_in, const int* in_sizes, int n_in,
                              void* d_out, int out_size, void* d_ws, size_t ws_size,
                              hipStream_t stream) {
  const float* x    = (const float*)d_in[0];
  const float* Wqkv = (const float*)d_in[1];
  const float* Wout = (const float*)d_in[2];

  unsigned short* xb    = (unsigned short*)d_ws;               // 8388608 el
  unsigned short* wqkvb = xb    + (size_t)8192 * 1024;         // 3145728 el
  unsigned short* woutb = wqkvb + (size_t)3072 * 1024;         // 1048576 el
  unsigned short* q_ws  = woutb + (size_t)1024 * 1024;
  unsigned short* k_ws  = q_ws  + (size_t)64 * 2048 * 64;
  unsigned short* vt_ws = k_ws  + (size_t)64 * 2048 * 64;
  unsigned short* opB   = vt_ws + (size_t)64 * 2048 * 64;      // +16.78 MB (split only)
  unsigned short* a_ws  = xb;   // alias: x_bf16 dead after QKV GEMM (also opA)
  float* lA = (float*)wqkvb;    // wqkv bf16 dead after gemm<0>; 1 MB carve
  float* lB = lA + 131072;

  const size_t NEED = ((size_t)8388608 + 3145728 + 1048576 + 3 * 8388608 + 8388608) * 2;

  cvtk3<<<2048, 256, 0, stream>>>((const float4*)x, (const float4*)Wqkv,
                                  (const float4*)Wout, (ushort4*)xb,
                                  (ushort4*)wqkvb, (ushort4*)woutb);

  gemm_k<0><<<dim3(24, 64), 256, 0, stream>>>(xb, wqkvb, q_ws, k_ws, vt_ws, nullptr);

  if (ws_size >= NEED) {
    attn_k<1><<<1024, 256, 0, stream>>>(q_ws, k_ws, vt_ws, nullptr, a_ws, opB, lA, lB);
    mergek<<<4096, 256, 0, stream>>>(a_ws, opB, lA, lB);
  } else {
    attn_k<0><<<512, 256, 0, stream>>>(q_ws, k_ws, vt_ws, a_ws, nullptr, nullptr, nullptr, nullptr);
  }

  gemm_k<1><<<dim3(8, 64), 256, 0, stream>>>(a_ws, woutb, nullptr, nullptr, nullptr, (float*)d_out);
}

// Round 22
// 204.522 us; speedup vs baseline: 1.0716x; 1.0716x over previous
//
#include <hip/hip_runtime.h>
#include <hip/hip_bf16.h>
#include <stdint.h>

#define DEVI __device__ __forceinline__

typedef float  f32x4 __attribute__((ext_vector_type(4)));
typedef short  s16x8 __attribute__((ext_vector_type(8)));

DEVI unsigned short bfbits(float f) {
  __hip_bfloat16 h = __float2bfloat16(f);
  return __builtin_bit_cast(unsigned short, h);
}

DEVI float fexp2(float x) { return __builtin_amdgcn_exp2f(x); }  // v_exp_f32 = 2^x

DEVI void mfma_bf16(f32x4& d, s16x8 a, s16x8 b) {
  asm("v_mfma_f32_16x16x32_bf16 %0, %1, %2, %0" : "+v"(d) : "v"(a), "v"(b));
}

DEVI void gload_lds16(const void* g, void* l) {
  __builtin_amdgcn_global_load_lds(
      (const __attribute__((address_space(1))) void*)g,
      (__attribute__((address_space(3))) void*)l, 16, 0, 0);
}

// ---------------- fp32 -> bf16 convert, all three tensors in one launch ----
__global__ void cvtk3(const float4* __restrict__ sx, const float4* __restrict__ sq,
                      const float4* __restrict__ sw, ushort4* __restrict__ dx,
                      ushort4* __restrict__ dq, ushort4* __restrict__ dw) {
  const int N1 = 2097152;            // x: 8192*1024/4
  const int N2 = 786432;             // Wqkv: 3072*1024/4
  const int N3 = 262144;             // Wout: 1024*1024/4
  int i = blockIdx.x * blockDim.x + threadIdx.x;
  int st = gridDim.x * blockDim.x;
  for (; i < N1 + N2 + N3; i += st) {
    const float4* s; ushort4* d; int j;
    if (i < N1)            { s = sx; d = dx; j = i; }
    else if (i < N1 + N2)  { s = sq; d = dq; j = i - N1; }
    else                   { s = sw; d = dw; j = i - N1 - N2; }
    float4 v = s[j];
    ushort4 o;
    o.x = bfbits(v.x); o.y = bfbits(v.y); o.z = bfbits(v.z); o.w = bfbits(v.w);
    d[j] = o;
  }
}

// ---------------- GEMM: C[M,N] = A[M,K] * BT[N,K]^T  (bf16 in, fp32 acc) ----
template<int EPI>
__global__ __launch_bounds__(256, 3) void gemm_k(
    const unsigned short* __restrict__ A,
    const unsigned short* __restrict__ BT,
    unsigned short* __restrict__ q_ws,
    unsigned short* __restrict__ k_ws,
    unsigned short* __restrict__ vt_ws,
    float* __restrict__ Cout)
{
  constexpr int K = 1024;
  __shared__ __align__(16) unsigned short Als[128 * 64];
  __shared__ __align__(16) unsigned short Bls[128 * 64];

  const int tid = threadIdx.x;
  const int w = tid >> 6, l = tid & 63;
  const int g = l >> 4, c = l & 15;
  const int wm = w >> 1, wn = w & 1;
  const int nb = blockIdx.x, mb = blockIdx.y;

  int srow[4], skof[4];
#pragma unroll
  for (int it = 0; it < 4; ++it) {
    int idx = (w * 4 + it) * 64 + l;
    srow[it] = idx >> 3;
    skof[it] = ((idx & 7) ^ (srow[it] & 7)) << 3;
  }

  f32x4 acc[4][4] = {};
  const unsigned short* Ab = A + (size_t)(mb * 128) * K;
  const unsigned short* Bb = BT + (size_t)(nb * 128) * K;

  for (int kt = 0; kt < K / 64; ++kt) {
    __syncthreads();
#pragma unroll
    for (int it = 0; it < 4; ++it) {
      gload_lds16(Ab + (size_t)srow[it] * K + kt * 64 + skof[it], &Als[(w * 4 + it) * 512]);
      gload_lds16(Bb + (size_t)srow[it] * K + kt * 64 + skof[it], &Bls[(w * 4 + it) * 512]);
    }
    __syncthreads();
#pragma unroll
    for (int kk = 0; kk < 2; ++kk) {
      s16x8 af[4], bfv[4];
#pragma unroll
      for (int mi = 0; mi < 4; ++mi) {
        int row = wm * 64 + mi * 16 + c;
        int slot = (kk * 4 + g) ^ (row & 7);
        af[mi] = *(const s16x8*)&Als[row * 64 + slot * 8];
      }
#pragma unroll
      for (int ni = 0; ni < 4; ++ni) {
        int row = wn * 64 + ni * 16 + c;
        int slot = (kk * 4 + g) ^ (row & 7);
        bfv[ni] = *(const s16x8*)&Bls[row * 64 + slot * 8];
      }
#pragma unroll
      for (int mi = 0; mi < 4; ++mi)
#pragma unroll
        for (int ni = 0; ni < 4; ++ni)
          mfma_bf16(acc[mi][ni], af[mi], bfv[ni]);
    }
  }

  if constexpr (EPI == 0) {
    const int csec = (nb * 128) >> 10;
    // Q prescale: (1/sqrt(64)) * log2(e) -> softmax runs in exp2 domain
    // (2^(s*log2e) == e^s exactly; softmax values identical)
    const float QSCALE = 0.125f * 1.44269504088896340736f;
#pragma unroll
    for (int mi = 0; mi < 4; ++mi) {
#pragma unroll
      for (int ni = 0; ni < 4; ++ni) {
        int ncol = nb * 128 + wn * 64 + ni * 16 + c;
        int f = ncol & 1023;
        int hh = f >> 6, dd = f & 63;
#pragma unroll
        for (int r = 0; r < 4; ++r) {
          int m = mb * 128 + wm * 64 + mi * 16 + 4 * g + r;
          int bb = m >> 11, ss = m & 2047;
          int bh = bb * 16 + hh;
          float v = acc[mi][ni][r];
          if (csec == 0)      q_ws[((size_t)bh * 2048 + ss) * 64 + dd] = bfbits(v * QSCALE);
          else if (csec == 1) k_ws[((size_t)bh * 2048 + ss) * 64 + dd] = bfbits(v);
          else                vt_ws[((size_t)bh * 64 + dd) * 2048 + ss] = bfbits(v);
        }
      }
    }
  } else {
#pragma unroll
    for (int mi = 0; mi < 4; ++mi)
#pragma unroll
      for (int ni = 0; ni < 4; ++ni) {
        int ncol = nb * 128 + wn * 64 + ni * 16 + c;
#pragma unroll
        for (int r = 0; r < 4; ++r) {
          int m = mb * 128 + wm * 64 + mi * 16 + 4 * g + r;
          Cout[(size_t)m * 1024 + ncol] = acc[mi][ni][r];
        }
      }
  }
}

// ---------------- flash attention (R20-EXACT structure + exp2 softmax) -----
// Round 22: R20 proven kernel (XCD swizzle, LDS K/V sharing,
// [sync][STAGE][sync][read] protocol) with ONE arithmetic change: softmax in
// exp2 domain (Q pre-scaled by 0.125*log2e in gemm epilogue; p = 2^s via
// bare v_exp_f32). Deletes 32 v_mul/tile from the VALU chain. m==0 softmax
// unchanged (scores bounded; scale-invariant).
__global__ __launch_bounds__(256) void attn_k(
    const unsigned short* __restrict__ q_ws,
    const unsigned short* __restrict__ k_ws,
    const unsigned short* __restrict__ vt_ws,
    unsigned short* __restrict__ a_ws)
{
  __shared__ __align__(16) unsigned short Klds[32 * 64];   // [kvrow][d], swz slot^=(row&7)
  __shared__ __align__(16) unsigned short Vlds[64 * 32];   // [d][kvcol], swz slot^=((row>>1)&3)
  __shared__ __align__(16) unsigned short P[4][64][40];    // per-wave [q][kpos]
  const int tid = threadIdx.x;
  const int w = tid >> 6, l = tid & 63;
  const int g = l >> 4, c = l & 15;
  const int bid = blockIdx.x;
  const int swz = (bid & 7) * 64 + (bid >> 3);   // bijective over 512 = 8*64
  const int wid = swz * 4 + w;
  const int bh = wid >> 5, qt = wid & 31;
  const int b = bh >> 4, h = bh & 15;
  const int qbase = qt * 64;

  const unsigned short* qp = q_ws + (size_t)bh * 2048 * 64;
  const unsigned short* kp = k_ws + (size_t)bh * 2048 * 64;
  const unsigned short* vp = vt_ws + (size_t)bh * 64 * 2048;

  const int krow  = 8 * w + (l >> 3);
  const int kslot = (l & 7) ^ (l >> 3);
  const int vrow  = 16 * w + (l >> 2);
  const int vslot = (l & 3) ^ ((l >> 3) & 3);

  s16x8 qa[4][2];
#pragma unroll
  for (int mi = 0; mi < 4; ++mi)
#pragma unroll
    for (int kk = 0; kk < 2; ++kk)
      qa[mi][kk] = *(const s16x8*)&qp[(size_t)(qbase + mi * 16 + c) * 64 + kk * 32 + g * 8];

  f32x4 o[4][4] = {};  // o[dt][mi]: O^T[d = dt*16+4g+r][q = mi*16+c]
  float lrun[4];
#pragma unroll
  for (int mi = 0; mi < 4; ++mi) lrun[mi] = 0.f;

  for (int kv = 0; kv < 2048; kv += 32) {
    __syncthreads();  // all waves done reading previous tile's Klds/Vlds
    gload_lds16(kp + (size_t)(kv + krow) * 64 + kslot * 8, &Klds[w * 512]);
    gload_lds16(vp + (size_t)vrow * 2048 + kv + vslot * 8, &Vlds[w * 512]);
    __syncthreads();  // staging complete (compiler drains vmcnt before barrier)

    s16x8 kb[2][2];
#pragma unroll
    for (int nt = 0; nt < 2; ++nt)
#pragma unroll
      for (int kk = 0; kk < 2; ++kk) {
        int row = nt * 16 + c;
        kb[nt][kk] = *(const s16x8*)&Klds[row * 64 + (((kk * 4 + g) ^ (row & 7)) * 8)];
      }

    f32x4 st[4][2] = {};
#pragma unroll
    for (int kk = 0; kk < 2; ++kk)
#pragma unroll
      for (int mi = 0; mi < 4; ++mi)
#pragma unroll
        for (int nt = 0; nt < 2; ++nt)
          mfma_bf16(st[mi][nt], kb[nt][kk], qa[mi][kk]);  // S^T = K * Q^T

#pragma unroll
    for (int mi = 0; mi < 4; ++mi) {
      f32x4 s0 = st[mi][0], s1 = st[mi][1];
      ushort4 w0, w1;
      float p00 = fexp2(s0[0]), p01 = fexp2(s0[1]);
      float p02 = fexp2(s0[2]), p03 = fexp2(s0[3]);
      float p10 = fexp2(s1[0]), p11 = fexp2(s1[1]);
      float p12 = fexp2(s1[2]), p13 = fexp2(s1[3]);
      lrun[mi] += ((p00 + p01) + (p02 + p03)) + ((p10 + p11) + (p12 + p13));
      w0.x = bfbits(p00); w0.y = bfbits(p01); w0.z = bfbits(p02); w0.w = bfbits(p03);
      w1.x = bfbits(p10); w1.y = bfbits(p11); w1.z = bfbits(p12); w1.w = bfbits(p13);
      *(ushort4*)&P[w][mi * 16 + c][4 * g]      = w0;   // ds_write_b64
      *(ushort4*)&P[w][mi * 16 + c][16 + 4 * g] = w1;
    }

    // FENCE: P writes drained, no compiler motion across (rule #18)
    asm volatile("s_waitcnt lgkmcnt(0)" ::: "memory");
    __builtin_amdgcn_sched_barrier(0);

    s16x8 pa[4], vb[4];
#pragma unroll
    for (int mi = 0; mi < 4; ++mi)
      pa[mi] = *(const s16x8*)&P[w][mi * 16 + c][g * 8];

    __builtin_amdgcn_sched_barrier(0);
    asm volatile("" ::: "memory");

#pragma unroll
    for (int dt = 0; dt < 4; ++dt) {
      int rd = dt * 16 + c;
      vb[dt] = *(const s16x8*)&Vlds[rd * 32 + ((g ^ ((rd >> 1) & 3)) * 8)];
    }
#pragma unroll
    for (int dt = 0; dt < 4; ++dt)
#pragma unroll
      for (int mi = 0; mi < 4; ++mi)
        mfma_bf16(o[dt][mi], vb[dt], pa[mi]);  // O^T += V^T * P^T
  }

#pragma unroll
  for (int mi = 0; mi < 4; ++mi) {
    float lv = lrun[mi];
    lv += __shfl_xor(lv, 16);
    lv += __shfl_xor(lv, 32);
    float inv = 1.0f / lv;
    size_t base = ((size_t)(b * 2048 + qbase + mi * 16 + c)) * 1024 + h * 64;
#pragma unroll
    for (int dt = 0; dt < 4; ++dt) {
      ushort4 ov;
      ov.x = bfbits(o[dt][mi][0] * inv);
      ov.y = bfbits(o[dt][mi][1] * inv);
      ov.z = bfbits(o[dt][mi][2] * inv);
      ov.w = bfbits(o[dt][mi][3] * inv);
      *(ushort4*)&a_ws[base + dt * 16 + 4 * g] = ov;  // 8B packed store
    }
  }
}

// ---------------- launcher ----------------
extern "C" void kernel_launch(void* const* d_in, const int* in_sizes, int n_in,
                              void* d_out, int out_size, void* d_ws, size_t ws_size,
                              hipStream_t stream) {
  const float* x    = (const float*)d_in[0];
  const float* Wqkv = (const float*)d_in[1];
  const float* Wout = (const float*)d_in[2];

  unsigned short* xb    = (unsigned short*)d_ws;
  unsigned short* wqkvb = xb    + (size_t)8192 * 1024;
  unsigned short* woutb = wqkvb + (size_t)3072 * 1024;
  unsigned short* q_ws  = woutb + (size_t)1024 * 1024;
  unsigned short* k_ws  = q_ws  + (size_t)64 * 2048 * 64;
  unsigned short* vt_ws = k_ws  + (size_t)64 * 2048 * 64;
  unsigned short* a_ws  = xb;  // alias: x_bf16 dead after QKV GEMM

  cvtk3<<<2048, 256, 0, stream>>>((const float4*)x, (const float4*)Wqkv,
                                  (const float4*)Wout, (ushort4*)xb,
                                  (ushort4*)wqkvb, (ushort4*)woutb);

  gemm_k<0><<<dim3(24, 64), 256, 0, stream>>>(xb, wqkvb, q_ws, k_ws, vt_ws, nullptr);
  attn_k<<<512, 256, 0, stream>>>(q_ws, k_ws, vt_ws, a_ws);
  gemm_k<1><<<dim3(8, 64), 256, 0, stream>>>(a_ws, woutb, nullptr, nullptr, nullptr, (float*)d_out);
}